// Round 4
// baseline (1163.610 us; speedup 1.0000x reference)
//
#include <hip/hip_runtime.h>
#include <hip/hip_bf16.h>
#include <cstdint>

#define NPTS 8192
#define DIM  128
#define NA   1024
#define KSEL 64

// ---------------------------------------------------------------------------
// Kernel 1: L1 distance matrix, 8x8 register blocking.
//   Rows 0..1023    : out1[anchor1[i]] vs out2   (dir 0)
//   Rows 1024..2047 : out2[anchor2[i]] vs out1   (dir 1)
// Tile BM=128 x BN=128, BK=32; 256 threads as 16x16, 8x8 acc per thread.
// Occupancy history:
//   r1: __launch_bounds__(256,3) -> 84 VGPR, full acc spill (2 GB scratch).
//   r2: no hint -> 240 VGPR, no spill, but 2 waves/SIMD -> latency-bound
//       (real VALU issue ~22%; LDS pipe ~80% loaded, queueing stalls).
//   r3 (this): amdgpu_waves_per_eu(3,4) -> cap 168 VGPR = 3 waves/SIMD.
//       Natural need ~135 regs (64 acc + 32 av + 8 bv + addr) -> no spill.
// LDS layout: tile[row][pos], pos = kchunk ^ ((row>>3)&7)  (16B chunks).
//   staging writes linear (t*16B), A reads 4-addr broadcast, B reads ~1 extra
//   cyc/read measured — conflicts negligible.
// ---------------------------------------------------------------------------
#define BM 128
#define BN 128
#define BK 32

__global__ __launch_bounds__(256) __attribute__((amdgpu_waves_per_eu(3, 4)))
void dist_kernel(const float* __restrict__ out1, const float* __restrict__ out2,
                 const int* __restrict__ anchor1, const int* __restrict__ anchor2,
                 float* __restrict__ Dmat) {
  __shared__ float At[BM * BK];   // [row][pos*4], pos = kchunk ^ ((row>>3)&7)
  __shared__ float Bt[BN * BK];

  const int t = threadIdx.x;
  int bid = blockIdx.x;
  bid = (bid & 7) * 128 + (bid >> 3);   // XCD-chunked swizzle (1024 % 8 == 0)
  const int mt  = bid & 15;             // 16 M-tiles, dir-major
  const int nt  = bid >> 4;             // 64 N-tiles
  const int dir = mt >> 3;
  const int i0  = (mt & 7) * BM;
  const int j0  = nt * BN;

  const float* __restrict__ Abase = dir ? out2 : out1;
  const float* __restrict__ Bbase = dir ? out1 : out2;
  const int* __restrict__ anc     = dir ? anchor2 : anchor1;

  // staging assignment: thread t stages rows (t>>3)+q*32, chunk pos t&7
  const int row0 = t >> 3;   // 0..31
  const int p    = t & 7;    // chunk position
  int anchQ[4];
#pragma unroll
  for (int q = 0; q < 4; ++q) anchQ[q] = anc[i0 + row0 + q * 32];

  const int ty = t >> 4;     // 0..15 : A rows ty*8..+8
  const int tx = t & 15;     // 0..15 : B rows tx*8..+8
  const int ty7_16 = (ty & 7) << 4;   // swizzle byte offset for A reads
  const int tx7_16 = (tx & 7) << 4;

  float acc[8][8];
#pragma unroll
  for (int r = 0; r < 8; ++r)
#pragma unroll
    for (int c = 0; c < 8; ++c) acc[r][c] = 0.f;

  for (int kk = 0; kk < DIM; kk += BK) {
    __syncthreads();   // protect LDS reuse (first iter: no-op cost)
#pragma unroll
    for (int q = 0; q < 4; ++q) {
      const int row = row0 + q * 32;
      const int swz = (row >> 3) & 7;
      float4 v = *(const float4*)(Abase + (size_t)anchQ[q] * DIM + kk + ((p ^ swz) << 2));
      *(float4*)(&At[row * BK + (p << 2)]) = v;   // byte = t*16 + q*4096 : linear
    }
#pragma unroll
    for (int q = 0; q < 4; ++q) {
      const int row = row0 + q * 32;
      const int swz = (row >> 3) & 7;
      float4 v = *(const float4*)(Bbase + (size_t)(j0 + row) * DIM + kk + ((p ^ swz) << 2));
      *(float4*)(&Bt[row * BK + (p << 2)]) = v;
    }
    __syncthreads();

#pragma unroll
    for (int kc = 0; kc < 8; ++kc) {
      const float4* avp = (const float4*)((const char*)At + ty * 1024 + (((kc << 4) ^ ty7_16)));
      const float4* bvp = (const float4*)((const char*)Bt + tx * 1024 + (((kc << 4) ^ tx7_16)));
      float4 av[8];
#pragma unroll
      for (int r = 0; r < 8; ++r) av[r] = avp[r * 8];   // imm offset r*128B
#pragma unroll
      for (int c = 0; c < 8; ++c) {
        const float4 bv = bvp[c * 8];
#pragma unroll
        for (int r = 0; r < 8; ++r) {
          acc[r][c] += fabsf(av[r].x - bv.x);
          acc[r][c] += fabsf(av[r].y - bv.y);
          acc[r][c] += fabsf(av[r].z - bv.z);
          acc[r][c] += fabsf(av[r].w - bv.w);
        }
      }
    }
  }

  const size_t orow0 = (size_t)(dir * NA + i0 + ty * 8);
#pragma unroll
  for (int r = 0; r < 8; ++r) {
    float4 v0 = make_float4(acc[r][0], acc[r][1], acc[r][2], acc[r][3]);
    float4 v1 = make_float4(acc[r][4], acc[r][5], acc[r][6], acc[r][7]);
    float* dst = Dmat + (orow0 + r) * NPTS + j0 + tx * 8;
    *(float4*)dst       = v0;
    *(float4*)(dst + 4) = v1;
  }
}

// ---------------------------------------------------------------------------
// Kernel 2: per (dir, anchor): exact top-64 via binary search on the uint32
// float key, then hinge-loss terms on the selected set. (passed rounds 0-3)
// ---------------------------------------------------------------------------
__global__ __launch_bounds__(256, 4)
void select_loss_kernel(const float* __restrict__ out1, const float* __restrict__ out2,
                        const float* __restrict__ ot,
                        const int* __restrict__ anchor1, const int* __restrict__ anchor2,
                        const float* __restrict__ Dmat, float* __restrict__ partials) {
  __shared__ float sd[NPTS];
  __shared__ float a_self[DIM];
  __shared__ float terms[KSEL];
  __shared__ int   sel[KSEL];
  __shared__ unsigned wred[4];
  __shared__ float sm_pos;
  __shared__ int sm_cnt, sm_tie;

  const int t   = threadIdx.x;
  const int b   = blockIdx.x;
  const int dir = b >> 10;
  const int i   = b & (NA - 1);

  const int a1i = anchor1[i];
  const int a2i = anchor2[i];
  const int ai_self = dir ? a2i : a1i;
  const float* __restrict__ selfB = dir ? out2 : out1;
  const float* __restrict__ othB  = dir ? out1 : out2;

  const float4* drow = (const float4*)(Dmat + (size_t)b * NPTS);
#pragma unroll
  for (int q = 0; q < 8; ++q) ((float4*)sd)[t + q * 256] = drow[t + q * 256];

  if (t < 32) ((float4*)a_self)[t] = ((const float4*)(selfB + (size_t)ai_self * DIM))[t];

  if (t == 0) { sm_cnt = 0; sm_tie = 0; }

  if (t < 64) {
    const float* r1 = out1 + (size_t)a1i * DIM;
    const float* r2 = out2 + (size_t)a2i * DIM;
    float pz = fabsf(r1[t] - r2[t]) + fabsf(r1[t + 64] - r2[t + 64]);
#pragma unroll
    for (int o = 32; o; o >>= 1) pz += __shfl_down(pz, o);
    if (t == 0) sm_pos = pz;
  }
  __syncthreads();

  unsigned keys[32];
#pragma unroll
  for (int q = 0; q < 32; ++q) keys[q] = __float_as_uint(sd[t + q * 256]);

  unsigned lo = 0u, hi = 0x7F800000u;
  while (lo < hi) {
    unsigned mid = lo + ((hi - lo) >> 1);
    unsigned c = 0;
#pragma unroll
    for (int q = 0; q < 32; ++q) c += (keys[q] <= mid) ? 1u : 0u;
#pragma unroll
    for (int o = 32; o; o >>= 1) c += __shfl_down(c, o);
    if ((t & 63) == 0) wred[t >> 6] = c;
    __syncthreads();
    c = wred[0] + wred[1] + wred[2] + wred[3];
    if (c >= 64u) hi = mid; else lo = mid + 1u;
    __syncthreads();
  }
  const unsigned T = lo;

  {
    unsigned c = 0;
#pragma unroll
    for (int q = 0; q < 32; ++q) c += (keys[q] < T) ? 1u : 0u;
#pragma unroll
    for (int o = 32; o; o >>= 1) c += __shfl_down(c, o);
    if ((t & 63) == 0) wred[t >> 6] = c;
  }
  __syncthreads();
  const int need = 64 - (int)(wred[0] + wred[1] + wred[2] + wred[3]);

#pragma unroll
  for (int q = 0; q < 32; ++q) {
    unsigned k = keys[q];
    bool take = false;
    if (k < T) take = true;
    else if (k == T) take = (atomicAdd(&sm_tie, 1) < need);
    if (take) {
      int s = atomicAdd(&sm_cnt, 1);
      sel[s] = t + q * 256;
    }
  }
  __syncthreads();

  {
    const int s  = t >> 2;
    const int tq = t & 3;
    const int j  = sel[s];
    const float w = dir ? ot[(size_t)j * NPTS + ai_self]
                        : ot[(size_t)ai_self * NPTS + j];
    const float* br = othB + (size_t)j * DIM;
    float dist = 0.f;
#pragma unroll
    for (int d = 0; d < 32; d += 4) {
      float4 bv = *(const float4*)(br + tq * 32 + d);
      dist += fabsf(a_self[tq * 32 + d + 0] - w * bv.x);
      dist += fabsf(a_self[tq * 32 + d + 1] - w * bv.y);
      dist += fabsf(a_self[tq * 32 + d + 2] - w * bv.z);
      dist += fabsf(a_self[tq * 32 + d + 3] - w * bv.w);
    }
    dist += __shfl_xor(dist, 1);
    dist += __shfl_xor(dist, 2);
    if (tq == 0) terms[s] = fmaxf(0.f, sm_pos + 1.0f - dist);
  }
  __syncthreads();

  if (t < 64) {
    float v = terms[t];
#pragma unroll
    for (int o = 32; o; o >>= 1) v += __shfl_down(v, o);
    if (t == 0) partials[b] = v;
  }
}

// ---------------------------------------------------------------------------
// Kernel 3: deterministic reduction of 2048 partials, scale by 1/(A*K).
// ---------------------------------------------------------------------------
__global__ __launch_bounds__(256)
void reduce_kernel(const float* __restrict__ partials, float* __restrict__ outp) {
  __shared__ float ws4[4];
  const int t = threadIdx.x;
  float v = 0.f;
#pragma unroll
  for (int q = 0; q < 8; ++q) v += partials[t + q * 256];
#pragma unroll
  for (int o = 32; o; o >>= 1) v += __shfl_down(v, o);
  if ((t & 63) == 0) ws4[t >> 6] = v;
  __syncthreads();
  if (t == 0) outp[0] = (ws4[0] + ws4[1] + ws4[2] + ws4[3]) * (1.0f / 65536.0f);
}

extern "C" void kernel_launch(void* const* d_in, const int* in_sizes, int n_in,
                              void* d_out, int out_size, void* d_ws, size_t ws_size,
                              hipStream_t stream) {
  (void)in_sizes; (void)n_in; (void)out_size; (void)ws_size;
  const float* out1  = (const float*)d_in[0];
  const float* out2  = (const float*)d_in[1];
  const float* ot    = (const float*)d_in[2];
  const int* anchor1 = (const int*)d_in[3];
  const int* anchor2 = (const int*)d_in[4];

  float* Dmat     = (float*)d_ws;                    // [2048][8192] f32, 64 MiB
  float* partials = Dmat + (size_t)2 * NA * NPTS;    // [2048]

  dist_kernel<<<dim3(16 * 64), dim3(256), 0, stream>>>(out1, out2, anchor1, anchor2, Dmat);
  select_loss_kernel<<<dim3(2 * NA), dim3(256), 0, stream>>>(out1, out2, ot, anchor1, anchor2,
                                                             Dmat, partials);
  reduce_kernel<<<dim3(1), dim3(256), 0, stream>>>(partials, (float*)d_out);
}

// Round 5
// 255.853 us; speedup vs baseline: 4.5480x; 4.5480x over previous
//
#include <hip/hip_runtime.h>
#include <hip/hip_bf16.h>
#include <cstdint>

#define NPTS 8192
#define DIM  128
#define NA   1024
#define KSEL 64

#define AS1 __attribute__((address_space(1)))
#define AS3 __attribute__((address_space(3)))

// ---------------------------------------------------------------------------
// Kernel 1: L1 distance matrix, 8x8 register blocking.
//   Rows 0..1023    : out1[anchor1[i]] vs out2   (dir 0)
//   Rows 1024..2047 : out2[anchor2[i]] vs out1   (dir 1)
// Tile BM=128 x BN=128, BK=32; 256 threads as 16x16, 8x8 acc per thread.
// Occupancy history:
//   r1/r3: ANY waves-per-eu hint (launch_bounds(,3) or amdgpu_waves_per_eu)
//          -> allocator minimizes to 84 VGPR and spills acc (2 GB scratch).
//   r2:    no hint -> 240 VGPR (scheduler keeps 8 staged float4 + addrs live
//          across compute) -> 2 waves/SIMD, latency-bound, 247 us.
//   r4 (this): staging via global_load_lds (direct HBM->LDS DMA, no VGPR
//          round-trip, no ds_write). Dest is wave-uniform base + lane*16
//          (our linear t*16 layout is exactly that); per-lane SOURCE carries
//          the swizzle (the legal combo per m104/m173). Natural VGPR ~130-150
//          -> 3 waves/SIMD without any hint.
// LDS layout: tile[row][pos], pos = kchunk ^ ((row>>3)&7)  (16B chunks).
// ---------------------------------------------------------------------------
#define BM 128
#define BN 128
#define BK 32

__global__ __launch_bounds__(256)
void dist_kernel(const float* __restrict__ out1, const float* __restrict__ out2,
                 const int* __restrict__ anchor1, const int* __restrict__ anchor2,
                 float* __restrict__ Dmat) {
  __shared__ float At[BM * BK];   // [row][pos*4], pos = kchunk ^ ((row>>3)&7)
  __shared__ float Bt[BN * BK];

  const int t = threadIdx.x;
  int bid = blockIdx.x;
  bid = (bid & 7) * 128 + (bid >> 3);   // XCD-chunked swizzle (1024 % 8 == 0)
  const int mt  = bid & 15;             // 16 M-tiles, dir-major
  const int nt  = bid >> 4;             // 64 N-tiles
  const int dir = mt >> 3;
  const int i0  = (mt & 7) * BM;
  const int j0  = nt * BN;

  const float* __restrict__ Abase = dir ? out2 : out1;
  const float* __restrict__ Bbase = dir ? out1 : out2;
  const int* __restrict__ anc     = dir ? anchor2 : anchor1;

  // staging assignment: thread t stages rows (t>>3)+q*32, chunk pos t&7.
  // LDS dest float index = t*4 + q*1024 (byte t*16 + q*4096): linear in t,
  // so lane0's address is the wave-uniform base global_load_lds needs.
  const int row0 = t >> 3;   // 0..31
  const int p    = t & 7;    // chunk position
  const float* srcA[4];
  const float* srcB[4];
#pragma unroll
  for (int q = 0; q < 4; ++q) {
    const int row = row0 + q * 32;
    const int swz = (row >> 3) & 7;
    const int koff = (p ^ swz) << 2;   // swizzled source dim offset
    srcA[q] = Abase + (size_t)anc[i0 + row] * DIM + koff;
    srcB[q] = Bbase + (size_t)(j0 + row) * DIM + koff;
  }

  const int ty = t >> 4;     // 0..15 : A rows ty*8..+8
  const int tx = t & 15;     // 0..15 : B rows tx*8..+8
  const int ty7_16 = (ty & 7) << 4;   // swizzle byte offset for A reads
  const int tx7_16 = (tx & 7) << 4;

  float acc[8][8];
#pragma unroll
  for (int r = 0; r < 8; ++r)
#pragma unroll
    for (int c = 0; c < 8; ++c) acc[r][c] = 0.f;

  for (int kk = 0; kk < DIM; kk += BK) {
    __syncthreads();   // previous compute done before DMA overwrites LDS
#pragma unroll
    for (int q = 0; q < 4; ++q) {
      __builtin_amdgcn_global_load_lds((const AS1 uint32_t*)(srcA[q] + kk),
                                       (AS3 uint32_t*)(&At[t * 4 + q * 1024]), 16, 0, 0);
      __builtin_amdgcn_global_load_lds((const AS1 uint32_t*)(srcB[q] + kk),
                                       (AS3 uint32_t*)(&Bt[t * 4 + q * 1024]), 16, 0, 0);
    }
    __syncthreads();   // compiler inserts vmcnt(0) drain here

#pragma unroll
    for (int kc = 0; kc < 8; ++kc) {
      const float4* avp = (const float4*)((const char*)At + ty * 1024 + (((kc << 4) ^ ty7_16)));
      const float4* bvp = (const float4*)((const char*)Bt + tx * 1024 + (((kc << 4) ^ tx7_16)));
      float4 av[8];
#pragma unroll
      for (int r = 0; r < 8; ++r) av[r] = avp[r * 8];   // imm offset r*128B
#pragma unroll
      for (int c = 0; c < 8; ++c) {
        const float4 bv = bvp[c * 8];
#pragma unroll
        for (int r = 0; r < 8; ++r) {
          acc[r][c] += fabsf(av[r].x - bv.x);
          acc[r][c] += fabsf(av[r].y - bv.y);
          acc[r][c] += fabsf(av[r].z - bv.z);
          acc[r][c] += fabsf(av[r].w - bv.w);
        }
      }
    }
  }

  const size_t orow0 = (size_t)(dir * NA + i0 + ty * 8);
#pragma unroll
  for (int r = 0; r < 8; ++r) {
    float4 v0 = make_float4(acc[r][0], acc[r][1], acc[r][2], acc[r][3]);
    float4 v1 = make_float4(acc[r][4], acc[r][5], acc[r][6], acc[r][7]);
    float* dst = Dmat + (orow0 + r) * NPTS + j0 + tx * 8;
    *(float4*)dst       = v0;
    *(float4*)(dst + 4) = v1;
  }
}

// ---------------------------------------------------------------------------
// Kernel 2: per (dir, anchor): exact top-64 via binary search on the uint32
// float key, then hinge-loss terms on the selected set. (passed rounds 0-3)
// ---------------------------------------------------------------------------
__global__ __launch_bounds__(256, 4)
void select_loss_kernel(const float* __restrict__ out1, const float* __restrict__ out2,
                        const float* __restrict__ ot,
                        const int* __restrict__ anchor1, const int* __restrict__ anchor2,
                        const float* __restrict__ Dmat, float* __restrict__ partials) {
  __shared__ float sd[NPTS];
  __shared__ float a_self[DIM];
  __shared__ float terms[KSEL];
  __shared__ int   sel[KSEL];
  __shared__ unsigned wred[4];
  __shared__ float sm_pos;
  __shared__ int sm_cnt, sm_tie;

  const int t   = threadIdx.x;
  const int b   = blockIdx.x;
  const int dir = b >> 10;
  const int i   = b & (NA - 1);

  const int a1i = anchor1[i];
  const int a2i = anchor2[i];
  const int ai_self = dir ? a2i : a1i;
  const float* __restrict__ selfB = dir ? out2 : out1;
  const float* __restrict__ othB  = dir ? out1 : out2;

  const float4* drow = (const float4*)(Dmat + (size_t)b * NPTS);
#pragma unroll
  for (int q = 0; q < 8; ++q) ((float4*)sd)[t + q * 256] = drow[t + q * 256];

  if (t < 32) ((float4*)a_self)[t] = ((const float4*)(selfB + (size_t)ai_self * DIM))[t];

  if (t == 0) { sm_cnt = 0; sm_tie = 0; }

  if (t < 64) {
    const float* r1 = out1 + (size_t)a1i * DIM;
    const float* r2 = out2 + (size_t)a2i * DIM;
    float pz = fabsf(r1[t] - r2[t]) + fabsf(r1[t + 64] - r2[t + 64]);
#pragma unroll
    for (int o = 32; o; o >>= 1) pz += __shfl_down(pz, o);
    if (t == 0) sm_pos = pz;
  }
  __syncthreads();

  unsigned keys[32];
#pragma unroll
  for (int q = 0; q < 32; ++q) keys[q] = __float_as_uint(sd[t + q * 256]);

  unsigned lo = 0u, hi = 0x7F800000u;
  while (lo < hi) {
    unsigned mid = lo + ((hi - lo) >> 1);
    unsigned c = 0;
#pragma unroll
    for (int q = 0; q < 32; ++q) c += (keys[q] <= mid) ? 1u : 0u;
#pragma unroll
    for (int o = 32; o; o >>= 1) c += __shfl_down(c, o);
    if ((t & 63) == 0) wred[t >> 6] = c;
    __syncthreads();
    c = wred[0] + wred[1] + wred[2] + wred[3];
    if (c >= 64u) hi = mid; else lo = mid + 1u;
    __syncthreads();
  }
  const unsigned T = lo;

  {
    unsigned c = 0;
#pragma unroll
    for (int q = 0; q < 32; ++q) c += (keys[q] < T) ? 1u : 0u;
#pragma unroll
    for (int o = 32; o; o >>= 1) c += __shfl_down(c, o);
    if ((t & 63) == 0) wred[t >> 6] = c;
  }
  __syncthreads();
  const int need = 64 - (int)(wred[0] + wred[1] + wred[2] + wred[3]);

#pragma unroll
  for (int q = 0; q < 32; ++q) {
    unsigned k = keys[q];
    bool take = false;
    if (k < T) take = true;
    else if (k == T) take = (atomicAdd(&sm_tie, 1) < need);
    if (take) {
      int s = atomicAdd(&sm_cnt, 1);
      sel[s] = t + q * 256;
    }
  }
  __syncthreads();

  {
    const int s  = t >> 2;
    const int tq = t & 3;
    const int j  = sel[s];
    const float w = dir ? ot[(size_t)j * NPTS + ai_self]
                        : ot[(size_t)ai_self * NPTS + j];
    const float* br = othB + (size_t)j * DIM;
    float dist = 0.f;
#pragma unroll
    for (int d = 0; d < 32; d += 4) {
      float4 bv = *(const float4*)(br + tq * 32 + d);
      dist += fabsf(a_self[tq * 32 + d + 0] - w * bv.x);
      dist += fabsf(a_self[tq * 32 + d + 1] - w * bv.y);
      dist += fabsf(a_self[tq * 32 + d + 2] - w * bv.z);
      dist += fabsf(a_self[tq * 32 + d + 3] - w * bv.w);
    }
    dist += __shfl_xor(dist, 1);
    dist += __shfl_xor(dist, 2);
    if (tq == 0) terms[s] = fmaxf(0.f, sm_pos + 1.0f - dist);
  }
  __syncthreads();

  if (t < 64) {
    float v = terms[t];
#pragma unroll
    for (int o = 32; o; o >>= 1) v += __shfl_down(v, o);
    if (t == 0) partials[b] = v;
  }
}

// ---------------------------------------------------------------------------
// Kernel 3: deterministic reduction of 2048 partials, scale by 1/(A*K).
// ---------------------------------------------------------------------------
__global__ __launch_bounds__(256)
void reduce_kernel(const float* __restrict__ partials, float* __restrict__ outp) {
  __shared__ float ws4[4];
  const int t = threadIdx.x;
  float v = 0.f;
#pragma unroll
  for (int q = 0; q < 8; ++q) v += partials[t + q * 256];
#pragma unroll
  for (int o = 32; o; o >>= 1) v += __shfl_down(v, o);
  if ((t & 63) == 0) ws4[t >> 6] = v;
  __syncthreads();
  if (t == 0) outp[0] = (ws4[0] + ws4[1] + ws4[2] + ws4[3]) * (1.0f / 65536.0f);
}

extern "C" void kernel_launch(void* const* d_in, const int* in_sizes, int n_in,
                              void* d_out, int out_size, void* d_ws, size_t ws_size,
                              hipStream_t stream) {
  (void)in_sizes; (void)n_in; (void)out_size; (void)ws_size;
  const float* out1  = (const float*)d_in[0];
  const float* out2  = (const float*)d_in[1];
  const float* ot    = (const float*)d_in[2];
  const int* anchor1 = (const int*)d_in[3];
  const int* anchor2 = (const int*)d_in[4];

  float* Dmat     = (float*)d_ws;                    // [2048][8192] f32, 64 MiB
  float* partials = Dmat + (size_t)2 * NA * NPTS;    // [2048]

  dist_kernel<<<dim3(16 * 64), dim3(256), 0, stream>>>(out1, out2, anchor1, anchor2, Dmat);
  select_loss_kernel<<<dim3(2 * NA), dim3(256), 0, stream>>>(out1, out2, ot, anchor1, anchor2,
                                                             Dmat, partials);
  reduce_kernel<<<dim3(1), dim3(256), 0, stream>>>(partials, (float*)d_out);
}

// Round 6
// 195.757 us; speedup vs baseline: 5.9441x; 1.3070x over previous
//
#include <hip/hip_runtime.h>
#include <hip/hip_bf16.h>
#include <cstdint>

#define NPTS 8192
#define DIM  128
#define NA   1024
#define KSEL 64

#define AS1 __attribute__((address_space(1)))
#define AS3 __attribute__((address_space(3)))

// ---------------------------------------------------------------------------
// Kernel 1: L1 distance matrix, 8x8 register blocking.
//   Rows 0..1023    : out1[anchor1[i]] vs out2   (dir 0)
//   Rows 1024..2047 : out2[anchor2[i]] vs out1   (dir 1)
// Tile BM=128 x BN=128, BK=32; 256 threads as 16x16, 8x8 acc per thread.
// Occupancy history:
//   r1/r3: ANY waves-per-eu hint -> allocator minimizes to 84 VGPR, spills
//          acc (2 GB scratch traffic, 1.1 ms). Hints are poison here.
//   r2:    no hint, full unroll -> 240 VGPR, 2 waves/SIMD, 247 us.
//   r4:    global_load_lds staging (no VGPR round-trip) -> 232 VGPR, 213 us.
//          Still 2 waves/SIMD: scheduler pipelines the unrolled kc-loop,
//          keeping ~2 iterations of av/bv live (~100 extra regs).
//   r5 (this): #pragma unroll 1 on kc (and kk) loop -> scheduler window is
//          one iteration, natural live set ~115 regs -> 3-4 waves/SIMD.
// LDS layout: tile[row][pos], pos = kchunk ^ ((row>>3)&7)  (16B chunks).
//   DMA dest is wave-uniform base + lane*16 (linear t*16); per-lane source
//   carries the swizzle (legal combo per m104/m173).
// ---------------------------------------------------------------------------
#define BM 128
#define BN 128
#define BK 32

__global__ __launch_bounds__(256)
void dist_kernel(const float* __restrict__ out1, const float* __restrict__ out2,
                 const int* __restrict__ anchor1, const int* __restrict__ anchor2,
                 float* __restrict__ Dmat) {
  __shared__ float At[BM * BK];   // [row][pos*4], pos = kchunk ^ ((row>>3)&7)
  __shared__ float Bt[BN * BK];

  const int t = threadIdx.x;
  int bid = blockIdx.x;
  bid = (bid & 7) * 128 + (bid >> 3);   // XCD-chunked swizzle (1024 % 8 == 0)
  const int mt  = bid & 15;             // 16 M-tiles, dir-major
  const int nt  = bid >> 4;             // 64 N-tiles
  const int dir = mt >> 3;
  const int i0  = (mt & 7) * BM;
  const int j0  = nt * BN;

  const float* __restrict__ Abase = dir ? out2 : out1;
  const float* __restrict__ Bbase = dir ? out1 : out2;
  const int* __restrict__ anc     = dir ? anchor2 : anchor1;

  // staging assignment: thread t stages rows (t>>3)+q*32, chunk pos t&7.
  // LDS dest float index = t*4 + q*1024 (byte t*16 + q*4096): linear in t.
  const int row0 = t >> 3;   // 0..31
  const int p    = t & 7;    // chunk position
  const float* srcA[4];
  const float* srcB[4];
#pragma unroll
  for (int q = 0; q < 4; ++q) {
    const int row = row0 + q * 32;
    const int swz = (row >> 3) & 7;
    const int koff = (p ^ swz) << 2;   // swizzled source dim offset
    srcA[q] = Abase + (size_t)anc[i0 + row] * DIM + koff;
    srcB[q] = Bbase + (size_t)(j0 + row) * DIM + koff;
  }

  const int ty = t >> 4;     // 0..15 : A rows ty*8..+8
  const int tx = t & 15;     // 0..15 : B rows tx*8..+8
  const int ty7_16 = (ty & 7) << 4;   // swizzle byte offset for A reads
  const int tx7_16 = (tx & 7) << 4;

  float acc[8][8];
#pragma unroll
  for (int r = 0; r < 8; ++r)
#pragma unroll
    for (int c = 0; c < 8; ++c) acc[r][c] = 0.f;

#pragma unroll 1
  for (int kk = 0; kk < DIM; kk += BK) {
    __syncthreads();   // previous compute done before DMA overwrites LDS
#pragma unroll
    for (int q = 0; q < 4; ++q) {
      __builtin_amdgcn_global_load_lds((const AS1 uint32_t*)(srcA[q] + kk),
                                       (AS3 uint32_t*)(&At[t * 4 + q * 1024]), 16, 0, 0);
      __builtin_amdgcn_global_load_lds((const AS1 uint32_t*)(srcB[q] + kk),
                                       (AS3 uint32_t*)(&Bt[t * 4 + q * 1024]), 16, 0, 0);
    }
    __syncthreads();   // compiler inserts vmcnt(0) drain here

#pragma unroll 1
    for (int kc = 0; kc < 8; ++kc) {
      const float4* avp = (const float4*)((const char*)At + ty * 1024 + (((kc << 4) ^ ty7_16)));
      const float4* bvp = (const float4*)((const char*)Bt + tx * 1024 + (((kc << 4) ^ tx7_16)));
      float4 av[8];
#pragma unroll
      for (int r = 0; r < 8; ++r) av[r] = avp[r * 8];   // imm offset r*128B
#pragma unroll
      for (int c = 0; c < 8; ++c) {
        const float4 bv = bvp[c * 8];
#pragma unroll
        for (int r = 0; r < 8; ++r) {
          acc[r][c] += fabsf(av[r].x - bv.x);
          acc[r][c] += fabsf(av[r].y - bv.y);
          acc[r][c] += fabsf(av[r].z - bv.z);
          acc[r][c] += fabsf(av[r].w - bv.w);
        }
      }
    }
  }

  const size_t orow0 = (size_t)(dir * NA + i0 + ty * 8);
#pragma unroll
  for (int r = 0; r < 8; ++r) {
    float4 v0 = make_float4(acc[r][0], acc[r][1], acc[r][2], acc[r][3]);
    float4 v1 = make_float4(acc[r][4], acc[r][5], acc[r][6], acc[r][7]);
    float* dst = Dmat + (orow0 + r) * NPTS + j0 + tx * 8;
    *(float4*)dst       = v0;
    *(float4*)(dst + 4) = v1;
  }
}

// ---------------------------------------------------------------------------
// Kernel 2: per (dir, anchor): exact top-64 via binary search on the uint32
// float key, then hinge-loss terms on the selected set. (passed rounds 0-4)
// ---------------------------------------------------------------------------
__global__ __launch_bounds__(256, 4)
void select_loss_kernel(const float* __restrict__ out1, const float* __restrict__ out2,
                        const float* __restrict__ ot,
                        const int* __restrict__ anchor1, const int* __restrict__ anchor2,
                        const float* __restrict__ Dmat, float* __restrict__ partials) {
  __shared__ float sd[NPTS];
  __shared__ float a_self[DIM];
  __shared__ float terms[KSEL];
  __shared__ int   sel[KSEL];
  __shared__ unsigned wred[4];
  __shared__ float sm_pos;
  __shared__ int sm_cnt, sm_tie;

  const int t   = threadIdx.x;
  const int b   = blockIdx.x;
  const int dir = b >> 10;
  const int i   = b & (NA - 1);

  const int a1i = anchor1[i];
  const int a2i = anchor2[i];
  const int ai_self = dir ? a2i : a1i;
  const float* __restrict__ selfB = dir ? out2 : out1;
  const float* __restrict__ othB  = dir ? out1 : out2;

  const float4* drow = (const float4*)(Dmat + (size_t)b * NPTS);
#pragma unroll
  for (int q = 0; q < 8; ++q) ((float4*)sd)[t + q * 256] = drow[t + q * 256];

  if (t < 32) ((float4*)a_self)[t] = ((const float4*)(selfB + (size_t)ai_self * DIM))[t];

  if (t == 0) { sm_cnt = 0; sm_tie = 0; }

  if (t < 64) {
    const float* r1 = out1 + (size_t)a1i * DIM;
    const float* r2 = out2 + (size_t)a2i * DIM;
    float pz = fabsf(r1[t] - r2[t]) + fabsf(r1[t + 64] - r2[t + 64]);
#pragma unroll
    for (int o = 32; o; o >>= 1) pz += __shfl_down(pz, o);
    if (t == 0) sm_pos = pz;
  }
  __syncthreads();

  unsigned keys[32];
#pragma unroll
  for (int q = 0; q < 32; ++q) keys[q] = __float_as_uint(sd[t + q * 256]);

  unsigned lo = 0u, hi = 0x7F800000u;
  while (lo < hi) {
    unsigned mid = lo + ((hi - lo) >> 1);
    unsigned c = 0;
#pragma unroll
    for (int q = 0; q < 32; ++q) c += (keys[q] <= mid) ? 1u : 0u;
#pragma unroll
    for (int o = 32; o; o >>= 1) c += __shfl_down(c, o);
    if ((t & 63) == 0) wred[t >> 6] = c;
    __syncthreads();
    c = wred[0] + wred[1] + wred[2] + wred[3];
    if (c >= 64u) hi = mid; else lo = mid + 1u;
    __syncthreads();
  }
  const unsigned T = lo;

  {
    unsigned c = 0;
#pragma unroll
    for (int q = 0; q < 32; ++q) c += (keys[q] < T) ? 1u : 0u;
#pragma unroll
    for (int o = 32; o; o >>= 1) c += __shfl_down(c, o);
    if ((t & 63) == 0) wred[t >> 6] = c;
  }
  __syncthreads();
  const int need = 64 - (int)(wred[0] + wred[1] + wred[2] + wred[3]);

#pragma unroll
  for (int q = 0; q < 32; ++q) {
    unsigned k = keys[q];
    bool take = false;
    if (k < T) take = true;
    else if (k == T) take = (atomicAdd(&sm_tie, 1) < need);
    if (take) {
      int s = atomicAdd(&sm_cnt, 1);
      sel[s] = t + q * 256;
    }
  }
  __syncthreads();

  {
    const int s  = t >> 2;
    const int tq = t & 3;
    const int j  = sel[s];
    const float w = dir ? ot[(size_t)j * NPTS + ai_self]
                        : ot[(size_t)ai_self * NPTS + j];
    const float* br = othB + (size_t)j * DIM;
    float dist = 0.f;
#pragma unroll
    for (int d = 0; d < 32; d += 4) {
      float4 bv = *(const float4*)(br + tq * 32 + d);
      dist += fabsf(a_self[tq * 32 + d + 0] - w * bv.x);
      dist += fabsf(a_self[tq * 32 + d + 1] - w * bv.y);
      dist += fabsf(a_self[tq * 32 + d + 2] - w * bv.z);
      dist += fabsf(a_self[tq * 32 + d + 3] - w * bv.w);
    }
    dist += __shfl_xor(dist, 1);
    dist += __shfl_xor(dist, 2);
    if (tq == 0) terms[s] = fmaxf(0.f, sm_pos + 1.0f - dist);
  }
  __syncthreads();

  if (t < 64) {
    float v = terms[t];
#pragma unroll
    for (int o = 32; o; o >>= 1) v += __shfl_down(v, o);
    if (t == 0) partials[b] = v;
  }
}

// ---------------------------------------------------------------------------
// Kernel 3: deterministic reduction of 2048 partials, scale by 1/(A*K).
// ---------------------------------------------------------------------------
__global__ __launch_bounds__(256)
void reduce_kernel(const float* __restrict__ partials, float* __restrict__ outp) {
  __shared__ float ws4[4];
  const int t = threadIdx.x;
  float v = 0.f;
#pragma unroll
  for (int q = 0; q < 8; ++q) v += partials[t + q * 256];
#pragma unroll
  for (int o = 32; o; o >>= 1) v += __shfl_down(v, o);
  if ((t & 63) == 0) ws4[t >> 6] = v;
  __syncthreads();
  if (t == 0) outp[0] = (ws4[0] + ws4[1] + ws4[2] + ws4[3]) * (1.0f / 65536.0f);
}

extern "C" void kernel_launch(void* const* d_in, const int* in_sizes, int n_in,
                              void* d_out, int out_size, void* d_ws, size_t ws_size,
                              hipStream_t stream) {
  (void)in_sizes; (void)n_in; (void)out_size; (void)ws_size;
  const float* out1  = (const float*)d_in[0];
  const float* out2  = (const float*)d_in[1];
  const float* ot    = (const float*)d_in[2];
  const int* anchor1 = (const int*)d_in[3];
  const int* anchor2 = (const int*)d_in[4];

  float* Dmat     = (float*)d_ws;                    // [2048][8192] f32, 64 MiB
  float* partials = Dmat + (size_t)2 * NA * NPTS;    // [2048]

  dist_kernel<<<dim3(16 * 64), dim3(256), 0, stream>>>(out1, out2, anchor1, anchor2, Dmat);
  select_loss_kernel<<<dim3(2 * NA), dim3(256), 0, stream>>>(out1, out2, ot, anchor1, anchor2,
                                                             Dmat, partials);
  reduce_kernel<<<dim3(1), dim3(256), 0, stream>>>(partials, (float*)d_out);
}